// Round 9
// baseline (207.288 us; speedup 1.0000x reference)
//
#include <hip/hip_runtime.h>
#include <math.h>

#define M_SPATIAL 2097152  // 128^3
#define BIAS 16384         // keeps every envelope term a positive exact int in fp32

__device__ __forceinline__ int imin2(int a, int b) { return a < b ? a : b; }

__device__ __forceinline__ float wave_redf(float v) {
#pragma unroll
  for (int o = 32; o > 0; o >>= 1) v += __shfl_down(v, o, 64);
  return v;
}
__device__ __forceinline__ double wave_redd(double v) {
#pragma unroll
  for (int o = 32; o > 0; o >>= 1) v += __shfl_down(v, o, 64);
  return v;
}

// part layout (doubles):
// [0..1023]=ce  [1024..2047]=p  [2048..3071]=pt  [3072..4095]=t  [4096..4607]=dist

// ---------------------------------------------------------------------------
// kAB: fused CE/dice partials + X-axis EDT.
// S[j=x][z] = (y==1 ? 1e6 : 0) + j^2 + BIAS  (positive exact ints).
// Envelope term e = fma(-2i, j, S[j]) > 0 -> min on float BIT PATTERNS as ints
// (v_min3_i32 folds from smin chains). Writes g = i^2 + best + yy^2
// ( = dX + yy^2 + BIAS : the Y-pass staging value, bias telescoped).
// ---------------------------------------------------------------------------
__global__ __launch_bounds__(256) void kAB_ce_edtx(const float* __restrict__ outputs,
                                                   const int* __restrict__ y,
                                                   float* __restrict__ g,
                                                   double* __restrict__ part) {
  __shared__ float S[128 * 32];    // 16 KB
  __shared__ float sm[4][4];
  int blk = blockIdx.x;            // b*512 + yy*4 + zc
  int b = blk >> 9, yy = (blk >> 2) & 127, zc = blk & 3;
  int t = threadIdx.x;
  size_t sp = (size_t)yy * 128 + (size_t)zc * 32;
  size_t tb = (size_t)b * M_SPATIAL + sp;
  const float* xc = outputs + (size_t)(2 * b + 1) * M_SPATIAL;

  float ce = 0.f, ps = 0.f, pts = 0.f, tsum = 0.f;
#pragma unroll
  for (int r = 0; r < 4; ++r) {
    int i4 = t + r * 256;
    int j = i4 >> 3, c = (i4 & 7) * 4;
    size_t off = (size_t)j * 16384 + c;
    const int4 vv = *(const int4*)(y + tb + off);
    const float4 xv = *(const float4*)(xc + sp + off);
    float j2b = (float)(j * j + BIAS);
#define ELEM(idx, yc, xcomp)                                                \
    {                                                                       \
      float tt = (yc == 1) ? 1.0f : 0.0f;                                   \
      S[j * 32 + c + idx] = tt * 1000000.f + j2b;                           \
      float xx = xcomp;                                                     \
      ce += fmaxf(xx, 0.0f) - xx * tt + log1pf(expf(-fabsf(xx)));           \
      float p = 1.0f / (1.0f + expf(-xx));                                  \
      ps += p; pts += p * tt; tsum += tt;                                   \
    }
    ELEM(0, vv.x, xv.x) ELEM(1, vv.y, xv.y) ELEM(2, vv.z, xv.z) ELEM(3, vv.w, xv.w)
#undef ELEM
  }
  __syncthreads();

  int zl = t & 31, ig = t >> 5;
  int best[16];
  float mc[16];
#pragma unroll
  for (int k = 0; k < 16; ++k) {
    best[k] = 0x7F7FFFFF;          // +FLT_MAX bit pattern
    mc[k] = -2.0f * (float)(ig * 16 + k);
  }
  {
    float jf0 = 0.f, jf1 = 1.f;
#pragma unroll 2
    for (int j = 0; j < 128; j += 2) {
      float h0 = S[j * 32 + zl];
      float h1 = S[(j + 1) * 32 + zl];
#pragma unroll
      for (int k = 0; k < 16; ++k) {
        float e0 = fmaf(mc[k], jf0, h0);
        float e1 = fmaf(mc[k], jf1, h1);
        best[k] = imin2(best[k], imin2(__float_as_int(e0), __float_as_int(e1)));
      }
      jf0 += 2.f; jf1 += 2.f;
    }
  }
  float yq = (float)(yy * yy);
  size_t ob = tb + zl;
#pragma unroll
  for (int k = 0; k < 16; ++k) {
    int i = ig * 16 + k;
    // g = i^2 + (best - BIAS) + yy^2 + BIAS  (Y-stage value, biases cancel)
    g[ob + (size_t)i * 16384] = (float)(i * i) + __int_as_float(best[k]) + yq;
  }

  float r0 = wave_redf(ce), r1 = wave_redf(ps), r2 = wave_redf(pts), r3 = wave_redf(tsum);
  int lane = t & 63, w = t >> 6;
  if (lane == 0) { sm[w][0] = r0; sm[w][1] = r1; sm[w][2] = r2; sm[w][3] = r3; }
  __syncthreads();
  if (t == 0) {
    part[blk]        = (double)(sm[0][0] + sm[1][0] + sm[2][0] + sm[3][0]);
    part[1024 + blk] = (double)(sm[0][1] + sm[1][1] + sm[2][1] + sm[3][1]);
    part[2048 + blk] = (double)(sm[0][2] + sm[1][2] + sm[2][2] + sm[3][2]);
    part[3072 + blk] = (double)(sm[0][3] + sm[1][3] + sm[2][3] + sm[3][3]);
  }
}

// ---------------------------------------------------------------------------
// kYZ: fused Y+Z pass + dist. 512 blocks x 512 threads: block = (b, x, y-half)
// -> exactly 2 blocks/CU (64 KB LDS each), balanced. Y-pass over the full
// staged slab for 64 i's; Bt repack with (y+z)&63 swizzle (conflict-free both
// sides); Z-pass + fused dist. Same int-min3 inner loop.
// ---------------------------------------------------------------------------
__global__ __launch_bounds__(512) void kYZ_dist(const float* __restrict__ g,
                                                const float* __restrict__ od,
                                                double* __restrict__ part) {
  __shared__ float S[128 * 128];   // 64 KB; first 32 KB reused as Bt after Y pass
  __shared__ float sred[8];
  int blk = blockIdx.x;            // b*256 + xx*2 + half
  int b = blk >> 8, xx = (blk >> 1) & 127, half = blk & 1;
  int t = threadIdx.x;
  size_t rb = (size_t)b * M_SPATIAL + (size_t)xx * 16384;

  // Z-pass thread mapping (also od prefetch): y_local=rl, z=ig2*16..+15.
  int rl = t & 63, ig2 = t >> 6;   // ig2 0..7
  size_t odb = (size_t)(2 * b + 1) * M_SPATIAL + (size_t)xx * 16384 +
               (size_t)(half * 64 + rl) * 128 + (size_t)ig2 * 16;
  const float4* o4 = (const float4*)(od + odb);
  float4 ov[4];
#pragma unroll
  for (int r = 0; r < 4; ++r) ov[r] = o4[r];

  // Stage full slab: S[y*128+z] (already biased by kAB), coalesced float4.
  const float4* g4 = (const float4*)(g + rb);
#pragma unroll
  for (int r = 0; r < 8; ++r) {
    int i4 = t + r * 512;
    *(float4*)(S + i4 * 4) = g4[i4];
  }
  __syncthreads();

  // --- Y pass: thread = (z=zl, ig); i = half*64 + ig*16 + k.
  int zl = t & 127, ig = t >> 7;   // ig 0..3
  int best[16];
  float mc[16];
#pragma unroll
  for (int k = 0; k < 16; ++k) {
    best[k] = 0x7F7FFFFF;
    mc[k] = -2.0f * (float)(half * 64 + ig * 16 + k);
  }
  {
    float jf0 = 0.f, jf1 = 1.f;
#pragma unroll 2
    for (int j = 0; j < 128; j += 2) {
      float h0 = S[j * 128 + zl];
      float h1 = S[(j + 1) * 128 + zl];
#pragma unroll
      for (int k = 0; k < 16; ++k) {
        float e0 = fmaf(mc[k], jf0, h0);
        float e1 = fmaf(mc[k], jf1, h1);
        best[k] = imin2(best[k], imin2(__float_as_int(e0), __float_as_int(e1)));
      }
      jf0 += 2.f; jf1 += 2.f;
    }
  }
  // Bt[z][y_local] = dY + z^2 + BIAS = i^2 + best + z^2 (biases telescope).
  float zq = (float)(zl * zl);
  float outv[16];
#pragma unroll
  for (int k = 0; k < 16; ++k) {
    int i = half * 64 + ig * 16 + k;
    outv[k] = (float)(i * i) + __int_as_float(best[k]) + zq;
  }
  __syncthreads();                 // all Y-pass reads of S done
#pragma unroll
  for (int k = 0; k < 16; ++k) {
    int il = ig * 16 + k;
    S[zl * 64 + ((il + zl) & 63)] = outv[k];   // swizzled: conflict-free
  }
  __syncthreads();

  // --- Z pass: thread = (y_local=rl, ig2); z_out = ig2*16 + k.
#pragma unroll
  for (int k = 0; k < 16; ++k) {
    best[k] = 0x7F7FFFFF;
    mc[k] = -2.0f * (float)(ig2 * 16 + k);
  }
  {
    float jf0 = 0.f, jf1 = 1.f;
#pragma unroll 2
    for (int j = 0; j < 128; j += 2) {
      float h0 = S[j * 64 + ((rl + j) & 63)];
      float h1 = S[(j + 1) * 64 + ((rl + j + 1) & 63)];
#pragma unroll
      for (int k = 0; k < 16; ++k) {
        float e0 = fmaf(mc[k], jf0, h0);
        float e1 = fmaf(mc[k], jf1, h1);
        best[k] = imin2(best[k], imin2(__float_as_int(e0), __float_as_int(e1)));
      }
      jf0 += 2.f; jf1 += 2.f;
    }
  }
  const float* of = (const float*)ov;
  float dist = 0.f;
#pragma unroll
  for (int k = 0; k < 16; ++k) {
    int zo = ig2 * 16 + k;
    float dv = (float)(zo * zo) + __int_as_float(best[k]) - (float)BIAS;  // exact
    if (dv > 0.f) dist += fabsf(of[k] - sqrtf(dv));
  }
  float r = wave_redf(dist);
  int lane = t & 63, w = t >> 6;
  if (lane == 0) sred[w] = r;
  __syncthreads();
  if (t == 0) {
    float s = 0.f;
#pragma unroll
    for (int w2 = 0; w2 < 8; ++w2) s += sred[w2];
    part[4096 + blk] = (double)s;
  }
}

// ---------------------------------------------------------------------------
// k_final: reduce partials (ce/p/pt/t: 1024 each; dist: 512), combine.
// ---------------------------------------------------------------------------
__global__ __launch_bounds__(256) void k_final(const double* __restrict__ part,
                                               const float* __restrict__ wptr,
                                               float* __restrict__ out) {
  int i = threadIdx.x;
  double ce  = part[i] + part[i + 256] + part[i + 512] + part[i + 768];
  double p0  = part[1024 + i] + part[1024 + i + 256];
  double p1  = part[1536 + i] + part[1536 + i + 256];
  double pt0 = part[2048 + i] + part[2048 + i + 256];
  double pt1 = part[2560 + i] + part[2560 + i + 256];
  double t0  = part[3072 + i] + part[3072 + i + 256];
  double t1  = part[3584 + i] + part[3584 + i + 256];
  double ds  = part[4096 + i] + part[4096 + i + 256];

  ce = wave_redd(ce); p0 = wave_redd(p0); p1 = wave_redd(p1);
  pt0 = wave_redd(pt0); pt1 = wave_redd(pt1);
  t0 = wave_redd(t0); t1 = wave_redd(t1); ds = wave_redd(ds);

  __shared__ double sm[4][8];
  int lane = threadIdx.x & 63, w = threadIdx.x >> 6;
  if (lane == 0) {
    sm[w][0] = ce; sm[w][1] = p0; sm[w][2] = p1; sm[w][3] = pt0;
    sm[w][4] = pt1; sm[w][5] = t0; sm[w][6] = t1; sm[w][7] = ds;
  }
  __syncthreads();
  if (threadIdx.x == 0) {
    double a[8];
    for (int q = 0; q < 8; ++q) a[q] = sm[0][q] + sm[1][q] + sm[2][q] + sm[3][q];
    double cem = a[0] / 4194304.0;
    double dice0 = (2.0 * a[3] + 1.0) / (a[1] + a[5] + 1.0);
    double dice1 = (2.0 * a[4] + 1.0) / (a[2] + a[6] + 1.0);
    double ldice = 1.0 - 0.5 * (dice0 + dice1);
    double msum = a[5] + a[6];
    double ldist = (msum == 0.0) ? 0.0 : a[7] / fmax(msum, 1e-12);
    out[0] = (float)(cem + ldice + (double)wptr[0] * ldist);
  }
}

extern "C" void kernel_launch(void* const* d_in, const int* in_sizes, int n_in,
                              void* d_out, int out_size, void* d_ws, size_t ws_size,
                              hipStream_t stream) {
  const float* outputs      = (const float*)d_in[0];
  const float* outputs_dist = (const float*)d_in[1];
  const int*   y            = (const int*)d_in[2];
  const float* wptr         = (const float*)d_in[3];
  float* out = (float*)d_out;

  double* part = (double*)d_ws;                    // 4608 doubles = 36 KiB
  float* g = (float*)((char*)d_ws + 65536);        // 16 MiB h field

  kAB_ce_edtx<<<1024, 256, 0, stream>>>(outputs, y, g, part);  // CE + X pass
  kYZ_dist<<<512, 512, 0, stream>>>(g, outputs_dist, part);    // Y+Z+dist
  k_final<<<1, 256, 0, stream>>>(part, wptr, out);
}

// Round 10
// 176.507 us; speedup vs baseline: 1.1744x; 1.1744x over previous
//
#include <hip/hip_runtime.h>
#include <math.h>

#define M_SPATIAL 2097152  // 128^3
#define MV4 (M_SPATIAL / 4)

__device__ __forceinline__ float wave_redf(float v) {
#pragma unroll
  for (int o = 32; o > 0; o >>= 1) v += __shfl_down(v, o, 64);
  return v;
}
__device__ __forceinline__ double wave_redd(double v) {
#pragma unroll
  for (int o = 32; o > 0; o >>= 1) v += __shfl_down(v, o, 64);
  return v;
}

// part layout (doubles):
// [0..1023]=ce  [1024..2047]=p  [2048..3071]=pt  [3072..4095]=t  [4096..5119]=dist

// ---------------------------------------------------------------------------
// kA: streaming CE + dice partials (float4/int4, per-block slots, no atomics).
// ---------------------------------------------------------------------------
__global__ __launch_bounds__(256) void kA_ce(const float4* __restrict__ outputs4,
                                             const int4* __restrict__ y4,
                                             double* __restrict__ part) {
  int blk = blockIdx.x;                 // 0..1023
  int base = blk * 1024;                // vec4 slots
  int b = (blk >= 512) ? 1 : 0;
  const float4* xc = outputs4 + (size_t)(b * 2 + 1) * MV4;
  float ce = 0.f, ps = 0.f, pts = 0.f, tsum = 0.f;
#pragma unroll
  for (int k = 0; k < 4; ++k) {
    int v4 = base + (int)threadIdx.x + k * 256;
    int s4 = v4 & (MV4 - 1);
    int4 yv = y4[v4];
    float4 x = xc[s4];
#define ELEM(c, yc)                                                         \
    {                                                                       \
      float t = (yc == 1) ? 1.0f : 0.0f;                                    \
      float xx = x.c;                                                       \
      ce += fmaxf(xx, 0.0f) - xx * t + log1pf(expf(-fabsf(xx)));            \
      float p = 1.0f / (1.0f + expf(-xx));                                  \
      ps += p; pts += p * t; tsum += t;                                     \
    }
    ELEM(x, yv.x) ELEM(y, yv.y) ELEM(z, yv.z) ELEM(w, yv.w)
#undef ELEM
  }
  float r0 = wave_redf(ce), r1 = wave_redf(ps), r2 = wave_redf(pts), r3 = wave_redf(tsum);
  __shared__ float sm[4][4];
  int lane = threadIdx.x & 63, w = threadIdx.x >> 6;
  if (lane == 0) { sm[w][0] = r0; sm[w][1] = r1; sm[w][2] = r2; sm[w][3] = r3; }
  __syncthreads();
  if (threadIdx.x == 0) {
    part[blk]        = (double)(sm[0][0] + sm[1][0] + sm[2][0] + sm[3][0]);
    part[1024 + blk] = (double)(sm[0][1] + sm[1][1] + sm[2][1] + sm[3][1]);
    part[2048 + blk] = (double)(sm[0][2] + sm[1][2] + sm[2][2] + sm[3][2]);
    part[3072 + blk] = (double)(sm[0][3] + sm[1][3] + sm[2][3] + sm[3][3]);
  }
}

// ---------------------------------------------------------------------------
// kB: X-axis EDT of the binary mask via two O(n) integer scans (branch-free),
// writing h = gX + y^2 as float (1e6 + y^2 when no bg in the line).
// Lane owns one x-line; df column in LDS is lane-private (no syncthreads).
// ---------------------------------------------------------------------------
__global__ __launch_bounds__(64) void kB_edtx(const int* __restrict__ y,
                                              float* __restrict__ g) {
  __shared__ int df[128 * 64];
  int blk = blockIdx.x;            // b*256 + yy*2 + zc
  int b  = blk >> 8;
  int yy = (blk >> 1) & 127;
  int zc = blk & 1;
  int l  = threadIdx.x;
  size_t base = (size_t)b * M_SPATIAL + (size_t)yy * 128 + (size_t)zc * 64 + l;

  int d = 200;
  for (int u0 = 0; u0 < 128; u0 += 16) {
    int yb[16];
#pragma unroll
    for (int k = 0; k < 16; ++k) yb[k] = y[base + (size_t)(u0 + k) * 16384];
#pragma unroll
    for (int k = 0; k < 16; ++k) {
      int fg = (yb[k] == 1);
      d = fg ? ((d < 200) ? d + 1 : 200) : 0;
      df[(u0 + k) * 64 + l] = d;
    }
  }
  float hinf = 1000000.f + (float)(yy * yy);
  float yy2f = (float)(yy * yy);
  int db = 200;
  for (int u0 = 127; u0 >= 0; u0 -= 16) {
    int fv[16];
#pragma unroll
    for (int k = 0; k < 16; ++k) fv[k] = df[(u0 - k) * 64 + l];
    float ov[16];
#pragma unroll
    for (int k = 0; k < 16; ++k) {
      db = (fv[k] > 0) ? ((db < 200) ? db + 1 : 200) : 0;
      int m = min(fv[k], db);
      ov[k] = (m >= 128) ? hinf : ((float)(m * m) + yy2f);
    }
#pragma unroll
    for (int k = 0; k < 16; ++k) g[base + (size_t)(u0 - k) * 16384] = ov[k];
  }
}

// ---------------------------------------------------------------------------
// kC: Y-axis pass, 2-slot/term envelope (j-pair form). In-place on g.
// Block = (b, x, 32-z chunk); thread: fixed z, 16 contiguous i(=y).
// Writes h' = dY + z^2 for the Z pass. All values exact ints < 2^21 in fp32.
// ---------------------------------------------------------------------------
__global__ __launch_bounds__(256) void kC_edty(float* __restrict__ g) {
  __shared__ float hl[128 * 33];   // hl[j*33 + zl]
  int blk = blockIdx.x;            // b*512 + xx*4 + zc
  int b = blk >> 9, xx = (blk >> 2) & 127, zc = blk & 3;
  int t = threadIdx.x;
  size_t rb = (size_t)b * M_SPATIAL + (size_t)xx * 16384 + (size_t)zc * 32;

  // Stage 128 rows x 32 z (float4, coalesced; LDS 2-way at most = free).
#pragma unroll
  for (int r = 0; r < 4; ++r) {
    int i4 = t + r * 256;          // 0..1023 float4 units
    int j = i4 >> 3, w = i4 & 7;   // row j, 4*w z-offset
    float4 v = *(const float4*)(g + rb + (size_t)j * 128 + 4 * w);
    hl[j * 33 + 4 * w + 0] = v.x;
    hl[j * 33 + 4 * w + 1] = v.y;
    hl[j * 33 + 4 * w + 2] = v.z;
    hl[j * 33 + 4 * w + 3] = v.w;
  }
  __syncthreads();

  int zl = t & 31, ig = t >> 5;
  float best[16], mc[16];
#pragma unroll
  for (int k = 0; k < 16; ++k) {
    best[k] = 3.0e38f;
    mc[k] = -2.0f * (float)(ig * 16 + k);
  }
#pragma unroll 2
  for (int j = 0; j < 128; j += 2) {
    float h0 = hl[j * 33 + zl];
    float h1 = hl[(j + 1) * 33 + zl];
    float jf0 = (float)j, jf1 = (float)(j + 1);
#pragma unroll
    for (int k = 0; k < 16; ++k) {
      float e0 = fmaf(mc[k], jf0, h0);
      float e1 = fmaf(mc[k], jf1, h1);
      best[k] = fminf(best[k], fminf(e0, e1));
    }
  }
  int gz = zc * 32 + zl;
  float zq = (float)(gz * gz);
  size_t ob = rb + zl;
#pragma unroll
  for (int k = 0; k < 16; ++k) {
    int i = ig * 16 + k;
    float dY = (float)(i * i) + best[k];   // exact int
    g[ob + (size_t)i * 128] = dY + zq;     // h for Z pass
  }
}

// ---------------------------------------------------------------------------
// kD: Z-axis pass (contiguous lines) + fused dist-loss partial.
// Block = (b, x, 32-y chunk): 4096 contiguous floats staged via LDS transpose.
// Thread: fixed y-line, 16 contiguous i(=z) -> od read as coalesced float4.
// ---------------------------------------------------------------------------
__global__ __launch_bounds__(256) void kD_edtz_dist(const float* __restrict__ g,
                                                    const float* __restrict__ od,
                                                    double* __restrict__ part) {
  __shared__ float hl[128 * 33];   // hl[z*33 + yl]
  __shared__ float sred[4];
  int blk = blockIdx.x;            // b*512 + xx*4 + yc
  int b = blk >> 9, xx = (blk >> 2) & 127, yc = blk & 3;
  int t = threadIdx.x;
  size_t rb = (size_t)b * M_SPATIAL + (size_t)xx * 16384 + (size_t)yc * 4096;
  int yl = t & 31, ig = t >> 5;

  // Prefetch od (this thread's 16 consecutive z) early to hide latency.
  size_t odb = (size_t)(2 * b + 1) * M_SPATIAL + (size_t)xx * 16384 +
               (size_t)yc * 4096 + (size_t)yl * 128 + (size_t)ig * 16;
  const float4* o4 = (const float4*)(od + odb);
  float4 ov[4];
#pragma unroll
  for (int r = 0; r < 4; ++r) ov[r] = o4[r];

  const float4* h4 = (const float4*)(g + rb);
#pragma unroll
  for (int r = 0; r < 4; ++r) {
    int i4 = t + r * 256;
    float4 v = h4[i4];
    int flat = i4 * 4;
    int z = flat & 127, yw = flat >> 7;  // z%4==0, all 4 comps same yw
    hl[(z + 0) * 33 + yw] = v.x;
    hl[(z + 1) * 33 + yw] = v.y;
    hl[(z + 2) * 33 + yw] = v.z;
    hl[(z + 3) * 33 + yw] = v.w;
  }
  __syncthreads();

  float best[16], mc[16];
#pragma unroll
  for (int k = 0; k < 16; ++k) {
    best[k] = 3.0e38f;
    mc[k] = -2.0f * (float)(ig * 16 + k);
  }
#pragma unroll 2
  for (int j = 0; j < 128; j += 2) {
    float h0 = hl[j * 33 + yl];
    float h1 = hl[(j + 1) * 33 + yl];
    float jf0 = (float)j, jf1 = (float)(j + 1);
#pragma unroll
    for (int k = 0; k < 16; ++k) {
      float e0 = fmaf(mc[k], jf0, h0);
      float e1 = fmaf(mc[k], jf1, h1);
      best[k] = fminf(best[k], fminf(e0, e1));
    }
  }
  const float* of = (const float*)ov;
  float dist = 0.f;
#pragma unroll
  for (int k = 0; k < 16; ++k) {
    int i = ig * 16 + k;
    float dv = (float)(i * i) + best[k];   // exact squared EDT
    if (dv > 0.f) dist += fabsf(of[k] - sqrtf(dv));
  }
  float r = wave_redf(dist);
  int lane = t & 63, w = t >> 6;
  if (lane == 0) sred[w] = r;
  __syncthreads();
  if (t == 0) part[4096 + blk] = (double)(sred[0] + sred[1] + sred[2] + sred[3]);
}

// ---------------------------------------------------------------------------
// k_final: reduce 5x1024 partials, combine to scalar loss.
// ---------------------------------------------------------------------------
__global__ __launch_bounds__(256) void k_final(const double* __restrict__ part,
                                               const float* __restrict__ wptr,
                                               float* __restrict__ out) {
  int i = threadIdx.x;
  double ce  = part[i] + part[i + 256] + part[i + 512] + part[i + 768];
  double p0  = part[1024 + i] + part[1024 + i + 256];
  double p1  = part[1536 + i] + part[1536 + i + 256];
  double pt0 = part[2048 + i] + part[2048 + i + 256];
  double pt1 = part[2560 + i] + part[2560 + i + 256];
  double t0  = part[3072 + i] + part[3072 + i + 256];
  double t1  = part[3584 + i] + part[3584 + i + 256];
  double ds  = part[4096 + i] + part[4096 + i + 256] + part[4096 + i + 512] + part[4096 + i + 768];

  ce = wave_redd(ce); p0 = wave_redd(p0); p1 = wave_redd(p1);
  pt0 = wave_redd(pt0); pt1 = wave_redd(pt1);
  t0 = wave_redd(t0); t1 = wave_redd(t1); ds = wave_redd(ds);

  __shared__ double sm[4][8];
  int lane = threadIdx.x & 63, w = threadIdx.x >> 6;
  if (lane == 0) {
    sm[w][0] = ce; sm[w][1] = p0; sm[w][2] = p1; sm[w][3] = pt0;
    sm[w][4] = pt1; sm[w][5] = t0; sm[w][6] = t1; sm[w][7] = ds;
  }
  __syncthreads();
  if (threadIdx.x == 0) {
    double a[8];
    for (int q = 0; q < 8; ++q) a[q] = sm[0][q] + sm[1][q] + sm[2][q] + sm[3][q];
    double cem = a[0] / 4194304.0;
    double dice0 = (2.0 * a[3] + 1.0) / (a[1] + a[5] + 1.0);
    double dice1 = (2.0 * a[4] + 1.0) / (a[2] + a[6] + 1.0);
    double ldice = 1.0 - 0.5 * (dice0 + dice1);
    double msum = a[5] + a[6];
    double ldist = (msum == 0.0) ? 0.0 : a[7] / fmax(msum, 1e-12);
    out[0] = (float)(cem + ldice + (double)wptr[0] * ldist);
  }
}

extern "C" void kernel_launch(void* const* d_in, const int* in_sizes, int n_in,
                              void* d_out, int out_size, void* d_ws, size_t ws_size,
                              hipStream_t stream) {
  const float* outputs      = (const float*)d_in[0];
  const float* outputs_dist = (const float*)d_in[1];
  const int*   y            = (const int*)d_in[2];
  const float* wptr         = (const float*)d_in[3];
  float* out = (float*)d_out;

  double* part = (double*)d_ws;                    // 5120 doubles = 40 KiB
  float* g = (float*)((char*)d_ws + 65536);        // 16 MiB h field

  kA_ce<<<1024, 256, 0, stream>>>((const float4*)outputs, (const int4*)y, part);
  kB_edtx<<<512, 64, 0, stream>>>(y, g);           // X scan -> h = gX + y^2
  kC_edty<<<1024, 256, 0, stream>>>(g);            // Y pass -> h = dY + z^2
  kD_edtz_dist<<<1024, 256, 0, stream>>>(g, outputs_dist, part);  // Z + dist
  k_final<<<1, 256, 0, stream>>>(part, wptr, out);
}